// Round 11
// baseline (263.174 us; speedup 1.0000x reference)
//
#include <hip/hip_runtime.h>
#include <stdint.h>

typedef int v4i  __attribute__((ext_vector_type(4)));
typedef int v16i __attribute__((ext_vector_type(16)));

// ---------------------------------------------------------------------------
// Kernel 1: quantize activations fp32 -> int8, plus per-row sums.
// ---------------------------------------------------------------------------
__global__ void quant_x_kernel(const float* __restrict__ x,
                               int8_t* __restrict__ xq,
                               int* __restrict__ sum_x,
                               const float* __restrict__ p_scale,
                               const int* __restrict__ p_zp,
                               int K) {
    const int row = blockIdx.x;
    const int t = threadIdx.x;
    const float s = p_scale[0];
    const float zpf = (float)p_zp[0];
    const float* xr = x + (size_t)row * K;
    int8_t* qr = xq + (size_t)row * K;
    int lsum = 0;
    const int nchunk = K >> 10;
    for (int i = 0; i < nchunk; ++i) {
        const int idx = (i << 10) + (t << 2);
        const float4 v = *reinterpret_cast<const float4*>(xr + idx);
        const float f0 = fminf(fmaxf(rintf(v.x / s) + zpf, -128.f), 127.f);
        const float f1 = fminf(fmaxf(rintf(v.y / s) + zpf, -128.f), 127.f);
        const float f2 = fminf(fmaxf(rintf(v.z / s) + zpf, -128.f), 127.f);
        const float f3 = fminf(fmaxf(rintf(v.w / s) + zpf, -128.f), 127.f);
        const int i0 = (int)f0, i1 = (int)f1, i2 = (int)f2, i3 = (int)f3;
        lsum += i0 + i1 + i2 + i3;
        const unsigned pk = (unsigned)(i0 & 255) | ((unsigned)(i1 & 255) << 8) |
                            ((unsigned)(i2 & 255) << 16) | ((unsigned)(i3 & 255) << 24);
        *reinterpret_cast<unsigned*>(qr + idx) = pk;
    }
    __shared__ int wsum[4];
    #pragma unroll
    for (int off = 32; off > 0; off >>= 1) lsum += __shfl_down(lsum, off);
    if ((t & 63) == 0) wsum[t >> 6] = lsum;
    __syncthreads();
    if (t == 0) sum_x[row] = wsum[0] + wsum[1] + wsum[2] + wsum[3];
}

// ---------------------------------------------------------------------------
// Kernel 2: pack weight int32 (int8-valued) -> int8, plus per-row sums.
// ---------------------------------------------------------------------------
__global__ void quant_w_kernel(const int* __restrict__ w,
                               int8_t* __restrict__ wq,
                               int* __restrict__ sum_w,
                               int K) {
    const int row = blockIdx.x;
    const int t = threadIdx.x;
    const int* wr_ = w + (size_t)row * K;
    int8_t* qr = wq + (size_t)row * K;
    int lsum = 0;
    const int nchunk = K >> 10;
    for (int i = 0; i < nchunk; ++i) {
        const int idx = (i << 10) + (t << 2);
        const int4 v = *reinterpret_cast<const int4*>(wr_ + idx);
        lsum += v.x + v.y + v.z + v.w;
        const unsigned pk = (unsigned)(v.x & 255) | ((unsigned)(v.y & 255) << 8) |
                            ((unsigned)(v.z & 255) << 16) | ((unsigned)(v.w & 255) << 24);
        *reinterpret_cast<unsigned*>(qr + idx) = pk;
    }
    __shared__ int wsum[4];
    #pragma unroll
    for (int off = 32; off > 0; off >>= 1) lsum += __shfl_down(lsum, off);
    if ((t & 63) == 0) wsum[t >> 6] = lsum;
    __syncthreads();
    if (t == 0) sum_w[row] = wsum[0] + wsum[1] + wsum[2] + wsum[3];
}

// ---------------------------------------------------------------------------
// Kernel 3: int8 GEMM, 256x256, 8 waves (2x4), 4-PHASE-PER-K-TILE fine
// interleave (i8 port of the verified 8-phase template; m201/m233 regime).
//
// K-tile = 128 B. Phase p == k-slot p (32 B). Per phase per wave:
//   6 ds_read_b128 (4 A-frags + 2 B-frags, slot p) ; 2 gload_lds (stage one
//   A-slice + one B-slice, 7 phases ahead) ; barrier ; setprio(1) ; 8 MFMA
//   (4mf x 2nf, slot p) ; setprio(0) ; vmcnt(6) ; barrier.
//
// LDS: [2 buf][4 slices][256 rows][32B] per op = 128 KiB. Slice = 8 KB.
//
// RACE PROOF (phases numbered g = 4t+p):
//  - slice g is STAGED at phase g-7, READ at phase g. vmcnt(6) at end of
//    each phase keeps only the last 3 phases' DMAs (2/phase, pure-DMA
//    stream -> in-order count is sound; the r7/r8 failure was MIXED
//    DMA+VGPR-load streams, structurally absent here) => staging of slice g
//    retired by end of phase g-4, published by that barrier. SAFE.
//  - staging at phase g overwrites slice g-8 (same buffer), last read at
//    phase g-1, separated by that phase's end barrier. SAFE.
//  - reads at phase g complete before phase-g MFMAs (compiler lgkmcnt),
//    which precede the end barrier; the overwrite issues after. SAFE.
//  - last tile: vmcnt(0) per phase drains the tail. SAFE.
//
// Bank conflicts (reads): layout [row][j'], j' = j ^ ((row>>4)&1). 32 lanes
// (rows r..r+31, fixed j): quad = 2*(row&15) + j' -> 32 distinct quads
// (enumerated: lanes 0-15 evens, 16-31 odds, 32-47 odds, 48-63 evens = 2
// lanes/bank = free minimum). Staged with LINEAR dest + inverse-swizzled
// source chunk (rule 21): src j = (lane&1) ^ ((lane>>5)&1); lane pairs read
// 32B contiguous per row.
// ---------------------------------------------------------------------------
#define BM 256
#define BN 256
#define BKB 128

__device__ __forceinline__ void gload_lds16(const void* g, void* l) {
    __builtin_amdgcn_global_load_lds(
        (const __attribute__((address_space(1))) unsigned int*)g,
        (__attribute__((address_space(3))) unsigned int*)l, 16, 0, 0);
}

#define MFMA_I8 __builtin_amdgcn_mfma_i32_32x32x32_i8

__global__ __launch_bounds__(512, 1)
void gemm_i8_kernel(const int8_t* __restrict__ xq,
                    const int8_t* __restrict__ wq,
                    const int* __restrict__ sum_x,
                    const int* __restrict__ sum_w,
                    const float* __restrict__ bias,
                    float* __restrict__ out,
                    const float* __restrict__ p_sa,
                    const int* __restrict__ p_zpa,
                    const float* __restrict__ p_sw,
                    const int* __restrict__ p_wzp,
                    int M, int N, int K) {
    __shared__ v4i ldsA[2][4][512];   // [buf][slice][unit16B] = 64 KiB
    __shared__ v4i ldsB[2][4][512];   // 128 KiB total

    const int tid = threadIdx.x;      // 512 threads = 8 waves
    const int lane = tid & 63;
    const int wid = tid >> 6;
    const int wr = wid >> 2;          // 0..1: rows wr*128..+127
    const int wc = wid & 3;           // 0..3: cols wc*64..+63

    // XCD-aware bijective swizzle (nwg = 512, %8 == 0)
    const int nwgy = M / BM;
    const int nwg = nwgy * (N / BN);
    const int bid = blockIdx.x;
    const int v = (bid & 7) * (nwg >> 3) + (bid >> 3);
    const int m0 = (v % nwgy) * BM;
    const int n0 = (v / nwgy) * BN;

    // ---- staging source: wave w covers rows w*32..+31 of a slice.
    // lane: row = w*32 + (lane>>1); src chunk j = (lane&1) ^ ((lane>>5)&1)
    // (inverse of the read swizzle g(row) = (row>>4)&1 = (lane>>5)&1 here).
    const int srow = wid * 32 + (lane >> 1);
    const int sj = (lane & 1) ^ ((lane >> 5) & 1);
    const int8_t* aS = xq + (size_t)(m0 + srow) * K + sj * 16;
    const int8_t* bS = wq + (size_t)(n0 + srow) * K + sj * 16;
    const int dbase = wid * 64;                 // wave-uniform dest (units)

    // ---- fragment reads: lane l: row = frag_base + (l&31), wants relative
    // chunk j = l>>5; stored at j' = j ^ ((row>>4)&1) = (l>>5) ^ ((l>>4)&1).
    const int jp = (lane >> 5) ^ ((lane >> 4) & 1);
    const int l31 = lane & 31;
    const int aU = (wr * 128 + l31) * 2 + jp;   // + mf*64
    const int bU = (wc * 64 + l31) * 2 + jp;    // + nf*64

    v16i acc[4][2] = {};
    const int NT = K / BKB;                     // 32

#define SLICE_STAGE(TT, S) do {                                               \
        gload_lds16(aS + (size_t)(TT) * BKB + (S) * 32,                       \
                    &ldsA[(TT) & 1][S][dbase]);                               \
        gload_lds16(bS + (size_t)(TT) * BKB + (S) * 32,                       \
                    &ldsB[(TT) & 1][S][dbase]);                               \
    } while (0)

    // ---- prologue: stage slices g = 0..6 (tile0 all, tile1 s0..s2)
    SLICE_STAGE(0, 0); SLICE_STAGE(0, 1); SLICE_STAGE(0, 2); SLICE_STAGE(0, 3);
    SLICE_STAGE(1, 0); SLICE_STAGE(1, 1); SLICE_STAGE(1, 2);
    asm volatile("s_waitcnt vmcnt(6)" ::: "memory");   // tile 0 retired
    __builtin_amdgcn_sched_barrier(0);
    __builtin_amdgcn_s_barrier();

    // ---- main loop: 4 phases per K-tile; phase P computes k-slot P and
    // stages slice g+7 (P==0 -> (t+1,3); P>=1 -> (t+2,P-1)).
#define PHASE(P) do {                                                         \
        const v4i* LA = ldsA[t & 1][P];                                       \
        const v4i* LB = ldsB[t & 1][P];                                       \
        const v4i a0 = LA[aU];                                                \
        const v4i a1 = LA[aU + 64];                                           \
        const v4i a2 = LA[aU + 128];                                          \
        const v4i a3 = LA[aU + 192];                                          \
        const v4i b0 = LB[bU];                                                \
        const v4i b1 = LB[bU + 64];                                           \
        if (P == 0) { if (t <= NT - 2) SLICE_STAGE(t + 1, 3); }               \
        else        { if (t <= NT - 3) SLICE_STAGE(t + 2, P - 1); }           \
        __builtin_amdgcn_s_barrier();                                         \
        __builtin_amdgcn_s_setprio(1);                                        \
        acc[0][0] = MFMA_I8(a0, b0, acc[0][0], 0, 0, 0);                      \
        acc[0][1] = MFMA_I8(a0, b1, acc[0][1], 0, 0, 0);                      \
        acc[1][0] = MFMA_I8(a1, b0, acc[1][0], 0, 0, 0);                      \
        acc[1][1] = MFMA_I8(a1, b1, acc[1][1], 0, 0, 0);                      \
        acc[2][0] = MFMA_I8(a2, b0, acc[2][0], 0, 0, 0);                      \
        acc[2][1] = MFMA_I8(a2, b1, acc[2][1], 0, 0, 0);                      \
        acc[3][0] = MFMA_I8(a3, b0, acc[3][0], 0, 0, 0);                      \
        acc[3][1] = MFMA_I8(a3, b1, acc[3][1], 0, 0, 0);                      \
        __builtin_amdgcn_s_setprio(0);                                        \
        if (t < NT - 1) { asm volatile("s_waitcnt vmcnt(6)" ::: "memory"); }  \
        else            { asm volatile("s_waitcnt vmcnt(0)" ::: "memory"); }  \
        __builtin_amdgcn_sched_barrier(0);                                    \
        __builtin_amdgcn_s_barrier();                                         \
    } while (0)

    for (int t = 0; t < NT; ++t) {
        PHASE(0); PHASE(1); PHASE(2); PHASE(3);
    }
#undef PHASE
#undef SLICE_STAGE

    // ---- epilogue: y = (acc - wzp*sum_x[m] - zp*sum_w[n] + K*zp*wzp)*(sa*sw) + bias[n]
    const float stot = p_sa[0] * p_sw[0];
    const int zpa = p_zpa[0];
    const int wzp = p_wzp[0];
    const int kzz = K * zpa * wzp;
    const int coll = lane & 31;
    const int rhi = (lane >> 5) * 4;

    #pragma unroll
    for (int cf = 0; cf < 2; ++cf) {
        const int cg = n0 + wc * 64 + cf * 32 + coll;
        const int sw = sum_w[cg];
        const float bb = bias[cg];
        #pragma unroll
        for (int rf = 0; rf < 4; ++rf) {
            const int rbase = m0 + wr * 128 + rf * 32 + rhi;
            #pragma unroll
            for (int r = 0; r < 16; ++r) {
                const int rowg = rbase + (r & 3) + 8 * (r >> 2);
                const int iv = acc[rf][cf][r] - wzp * sum_x[rowg] - zpa * sw + kzz;
                out[(size_t)rowg * N + cg] = (float)iv * stot + bb;
            }
        }
    }
}

// ---------------------------------------------------------------------------
extern "C" void kernel_launch(void* const* d_in, const int* in_sizes, int n_in,
                              void* d_out, int out_size, void* d_ws, size_t ws_size,
                              hipStream_t stream) {
    const float* x     = (const float*)d_in[0];
    const int*   w     = (const int*)d_in[1];
    const float* bias  = (const float*)d_in[2];
    const float* p_sa  = (const float*)d_in[3];
    const int*   p_zpa = (const int*)d_in[4];
    const float* p_sw  = (const float*)d_in[5];
    const int*   p_wzp = (const int*)d_in[6];

    const int N = in_sizes[2];             // OUT
    const int K = in_sizes[1] / N;         // IN
    const int M = in_sizes[0] / K;         // B*S

    int8_t* xq = (int8_t*)d_ws;
    int8_t* wq = xq + (size_t)M * K;
    int* sum_x = (int*)(wq + (size_t)N * K);
    int* sum_w = sum_x + M;

    quant_x_kernel<<<M, 256, 0, stream>>>(x, xq, sum_x, p_sa, p_zpa, K);
    quant_w_kernel<<<N, 256, 0, stream>>>(w, wq, sum_w, K);

    const int nwg = (M / BM) * (N / BN);   // 512
    gemm_i8_kernel<<<nwg, 512, 0, stream>>>(xq, wq, sum_x, sum_w, bias,
                                            (float*)d_out, p_sa, p_zpa, p_sw, p_wzp,
                                            M, N, K);
}